// Round 3
// baseline (1574.166 us; speedup 1.0000x reference)
//
#include <hip/hip_runtime.h>
#include <math.h>

#define NN 100000
#define NE 800000
#define ET (NN + NE)   /* 900000 edges incl self-loops */
#define GIN 64
#define CH 32
#define NH 4
#define NG 256
#define SLOPE 0.2f
#define NB1 ((NN + 255) / 256)   /* 391 scan blocks */

// ---- node transform: XL = X@Wl+bl, XR = X@Wr+br ----
// W columns in registers (split across TPC lanes), X tile staged in LDS.
// threads = 2*M*TPC = 256. Each thread: col = t/TPC, k-slice = t%TPC.
template<int K, int M, int TPC, int NPB>
__global__ void transform_kernel(const float* __restrict__ X,
                                 const float* __restrict__ Wl, const float* __restrict__ bl,
                                 const float* __restrict__ Wr, const float* __restrict__ br,
                                 float* __restrict__ XL, float* __restrict__ XR, int n)
{
    constexpr int KR = K / TPC;            // W regs per thread
    __shared__ float sX[NPB * K];
    const int t   = threadIdx.x;
    const int col = t / TPC;               // 0..2M-1
    const int ks  = t % TPC;
    const int k0  = ks * KR;
    const int cw  = (col < M) ? col : col - M;
    const float* W = (col < M) ? Wl : Wr;
    float wreg[KR];
    #pragma unroll
    for (int k = 0; k < KR; ++k) wreg[k] = W[(size_t)(k0 + k) * M + cw];
    const float bias = (ks == 0) ? ((col < M) ? bl[cw] : br[cw]) : 0.f;
    float* const outp = (col < M) ? XL : XR;

    const int base   = blockIdx.x * NPB;
    const int nvalid = (n - base < NPB) ? (n - base) : NPB;

    // stage X tile (coalesced float4)
    constexpr int QTOT = NPB * K / 4;
    for (int q = t; q < QTOT; q += 256) {
        const int node = q / (K / 4);
        const int qq   = q % (K / 4);
        float4 v = (node < nvalid)
                       ? *(const float4*)(X + (size_t)(base + node) * K + qq * 4)
                       : make_float4(0.f, 0.f, 0.f, 0.f);
        *(float4*)(sX + node * K + qq * 4) = v;
    }
    __syncthreads();

    for (int nn0 = 0; nn0 < nvalid; nn0 += 2) {
        float acc0 = bias, acc1 = bias;
        const float* x0 = sX + nn0 * K + k0;
        const float* x1 = sX + (nn0 + 1) * K + k0;   // safe: NPB even, zero-filled
        const bool has1 = (nn0 + 1 < nvalid);
        #pragma unroll
        for (int kq = 0; kq < KR / 4; ++kq) {
            const float4 a = *(const float4*)(x0 + kq * 4);
            acc0 = fmaf(a.x, wreg[kq * 4 + 0], acc0);
            acc0 = fmaf(a.y, wreg[kq * 4 + 1], acc0);
            acc0 = fmaf(a.z, wreg[kq * 4 + 2], acc0);
            acc0 = fmaf(a.w, wreg[kq * 4 + 3], acc0);
            const float4 b = *(const float4*)(x1 + kq * 4);
            acc1 = fmaf(b.x, wreg[kq * 4 + 0], acc1);
            acc1 = fmaf(b.y, wreg[kq * 4 + 1], acc1);
            acc1 = fmaf(b.z, wreg[kq * 4 + 2], acc1);
            acc1 = fmaf(b.w, wreg[kq * 4 + 3], acc1);
        }
        if (TPC > 1) {
            #pragma unroll
            for (int off = 1; off < TPC; off <<= 1) {
                acc0 += __shfl_xor(acc0, off);
                acc1 += __shfl_xor(acc1, off);
            }
        }
        if (ks == 0) {
            outp[(size_t)(base + nn0) * M + cw] = acc0;
            if (has1) outp[(size_t)(base + nn0 + 1) * M + cw] = acc1;
        }
    }
}

// ---- CSR build: histogram of dst ----
__global__ void hist_kernel(const int* __restrict__ edst, int* __restrict__ deg)
{
    int e = blockIdx.x * 256 + threadIdx.x;
    if (e >= ET) return;
    int d = (e < NE) ? edst[e] : (e - NE);
    atomicAdd(deg + d, 1);
}

// ---- 3-kernel exclusive scan: rowstart[i] = sum(deg[0..i-1]) ----
__global__ void scan1_kernel(const int* __restrict__ deg, int* __restrict__ rowstart,
                             int* __restrict__ bsum)
{
    __shared__ int lds[256];
    int t = threadIdx.x, idx = blockIdx.x * 256 + t;
    int v = (idx < NN) ? deg[idx] : 0;
    lds[t] = v;
    __syncthreads();
    #pragma unroll
    for (int off = 1; off < 256; off <<= 1) {
        int add = (t >= off) ? lds[t - off] : 0;
        __syncthreads();
        lds[t] += add;
        __syncthreads();
    }
    if (idx < NN) rowstart[idx + 1] = lds[t];   // inclusive, block-local
    if (t == 255) bsum[blockIdx.x] = lds[255];
}

__global__ void scan2_kernel(int* __restrict__ bsum)   // exclusive scan of NB1 sums
{
    __shared__ int lds[512];
    int t = threadIdx.x;
    int v = (t < NB1) ? bsum[t] : 0;
    lds[t] = v;
    __syncthreads();
    #pragma unroll
    for (int off = 1; off < 512; off <<= 1) {
        int add = (t >= off) ? lds[t - off] : 0;
        __syncthreads();
        lds[t] += add;
        __syncthreads();
    }
    if (t < NB1) bsum[t] = lds[t] - v;
}

__global__ void scan3_kernel(int* __restrict__ rowstart, const int* __restrict__ bsum)
{
    int idx = blockIdx.x * 256 + threadIdx.x;
    if (idx == 0) rowstart[0] = 0;
    if (idx < NN) rowstart[idx + 1] += bsum[blockIdx.x];
}

// ---- CSR scatter: fill src ids per dst row ----
__global__ void scatter_kernel(const int* __restrict__ esrc, const int* __restrict__ edst,
                               const int* __restrict__ rowstart,
                               int* __restrict__ cursor, int* __restrict__ csr_src)
{
    int e = blockIdx.x * 256 + threadIdx.x;
    if (e >= ET) return;
    int s, d;
    if (e < NE) { s = esrc[e]; d = edst[e]; } else { s = e - NE; d = s; }
    int pos = rowstart[d] + atomicAdd(cursor + d, 1);
    csr_src[pos] = s;
}

// ---- layer 1 fused GATv2 (H=4, C=32): one wave per dst node, online softmax ----
__global__ void gat1_kernel(const int* __restrict__ rowstart, const int* __restrict__ csr_src,
                            const float* __restrict__ XL, const float* __restrict__ XR,
                            const float* __restrict__ att, const float* __restrict__ bias,
                            float* __restrict__ H1)
{
    int node = blockIdx.x * 4 + (threadIdx.x >> 6);
    if (node >= NN) return;
    const int lane = threadIdx.x & 63;
    const int c0 = lane * 2;
    const float2 xr = *(const float2*)(XR + (size_t)node * 128 + c0);
    const float2 at = *(const float2*)(att + c0);
    const int beg = rowstart[node], end = rowstart[node + 1];
    float m = -INFINITY, ssum = 0.f, acc0 = 0.f, acc1 = 0.f;
    for (int i = beg; i < end; ++i) {
        const int s = csr_src[i];
        const float2 xl = *(const float2*)(XL + (size_t)s * 128 + c0);
        float v0 = xl.x + xr.x; v0 = v0 > 0.f ? v0 : SLOPE * v0;
        float v1 = xl.y + xr.y; v1 = v1 > 0.f ? v1 : SLOPE * v1;
        float p = fmaf(v0, at.x, v1 * at.y);
        p += __shfl_xor(p, 1);
        p += __shfl_xor(p, 2);
        p += __shfl_xor(p, 4);
        p += __shfl_xor(p, 8);       // p = alpha for head (lane>>4)
        float ea;
        if (p > m) {
            float sc = expf(m - p);  // exp(-inf)=0 on first edge
            ssum *= sc; acc0 *= sc; acc1 *= sc;
            m = p; ea = 1.f;
        } else {
            ea = expf(p - m);
        }
        ssum += ea;
        acc0 = fmaf(ea, xl.x, acc0);
        acc1 = fmaf(ea, xl.y, acc1);
    }
    const float inv = 1.f / (ssum + 1e-16f);
    float o0 = acc0 * inv + bias[c0];
    float o1 = acc1 * inv + bias[c0 + 1];
    o0 = o0 > 0.f ? o0 : expm1f(o0);
    o1 = o1 > 0.f ? o1 : expm1f(o1);
    *(float2*)(H1 + (size_t)node * 128 + c0) = make_float2(o0, o1);
}

// ---- layer 2 fused GATv2 (H=1, C=32): one half-wave per dst node ----
__global__ void gat2_kernel(const int* __restrict__ rowstart, const int* __restrict__ csr_src,
                            const float* __restrict__ XL, const float* __restrict__ XR,
                            const float* __restrict__ att,
                            float* __restrict__ H2)
{
    int node = blockIdx.x * 8 + (threadIdx.x >> 5);
    if (node >= NN) return;
    const int c = threadIdx.x & 31;
    const float xr = XR[(size_t)node * 32 + c];
    const float at = att[c];
    const int beg = rowstart[node], end = rowstart[node + 1];
    float m = -INFINITY, ssum = 0.f, acc = 0.f;
    for (int i = beg; i < end; ++i) {
        const int s = csr_src[i];
        const float xl = XL[(size_t)s * 32 + c];
        float v = xl + xr; v = v > 0.f ? v : SLOPE * v;
        float p = v * at;
        p += __shfl_xor(p, 1);
        p += __shfl_xor(p, 2);
        p += __shfl_xor(p, 4);
        p += __shfl_xor(p, 8);
        p += __shfl_xor(p, 16);
        float ea;
        if (p > m) {
            float sc = expf(m - p);
            ssum *= sc; acc *= sc;
            m = p; ea = 1.f;
        } else {
            ea = expf(p - m);
        }
        ssum += ea;
        acc = fmaf(ea, xl, acc);
    }
    H2[(size_t)node * 32 + c] = acc / (ssum + 1e-16f);
}

// ---- mean-pool (batch sorted: run-length accumulate, then atomic flush) ----
__global__ void pool_kernel(const float* __restrict__ h2, const float* __restrict__ bias2,
                            const int* __restrict__ batch,
                            float* __restrict__ pool, float* __restrict__ cnt)
{
    const int c    = threadIdx.x & 31;
    const int slot = threadIdx.x >> 5;     // 0..7
    const int base = blockIdx.x * 256;
    const float b = bias2[c];
    float acc = 0.f, cacc = 0.f;
    int curg = -1;
    for (int i = slot; i < 256; i += 8) {
        int node = base + i;
        if (node >= NN) break;
        int g = batch[node];
        if (g != curg) {
            if (curg >= 0) {
                atomicAdd(pool + (size_t)curg * 32 + c, acc);
                if (c == 0) atomicAdd(cnt + curg, cacc);
            }
            acc = 0.f; cacc = 0.f; curg = g;
        }
        acc += h2[(size_t)node * 32 + c] + b;
        cacc += 1.f;
    }
    if (curg >= 0) {
        atomicAdd(pool + (size_t)curg * 32 + c, acc);
        if (c == 0) atomicAdd(cnt + curg, cacc);
    }
}

// ---- per-graph head MLP: out = relu(pooled@Wh1+bh1)@Wh2 + bh2 ----
__global__ void head_kernel(const float* __restrict__ pool, const float* __restrict__ cnt,
                            const float* __restrict__ Wh1, const float* __restrict__ bh1,
                            const float* __restrict__ Wh2, const float* __restrict__ bh2,
                            float* __restrict__ out)
{
    int g = blockIdx.x;
    int c = threadIdx.x;      // 0..63
    float partial = 0.f;
    if (c < 32) {
        float invc = 1.f / fmaxf(cnt[g], 1.f);
        float acc = bh1[c];
        #pragma unroll
        for (int k = 0; k < 32; ++k)
            acc = fmaf(pool[g * 32 + k] * invc, Wh1[k * 32 + c], acc);
        float z = fmaxf(acc, 0.f);
        partial = z * Wh2[c];
    }
    #pragma unroll
    for (int off = 32; off >= 1; off >>= 1)
        partial += __shfl_down(partial, off);
    if (c == 0) out[g] = partial + bh2[0];
}

extern "C" void kernel_launch(void* const* d_in, const int* in_sizes, int n_in,
                              void* d_out, int out_size, void* d_ws, size_t ws_size,
                              hipStream_t stream)
{
    const float* x     = (const float*)d_in[0];
    const int*   ei    = (const int*)d_in[1];
    const int*   batch = (const int*)d_in[2];
    const float* Wl1   = (const float*)d_in[3];
    const float* bl1   = (const float*)d_in[4];
    const float* Wr1   = (const float*)d_in[5];
    const float* br1   = (const float*)d_in[6];
    const float* att1  = (const float*)d_in[7];
    const float* bias1 = (const float*)d_in[8];
    const float* Wl2   = (const float*)d_in[9];
    const float* bl2   = (const float*)d_in[10];
    const float* Wr2   = (const float*)d_in[11];
    const float* br2   = (const float*)d_in[12];
    const float* att2  = (const float*)d_in[13];
    const float* bias2 = (const float*)d_in[14];
    const float* Wh1   = (const float*)d_in[15];
    const float* bh1   = (const float*)d_in[16];
    const float* Wh2   = (const float*)d_in[17];
    const float* bh2   = (const float*)d_in[18];
    const int* esrc = ei;
    const int* edst = ei + NE;

    // ---- workspace layout ----
    float* ws  = (float*)d_ws;
    float* xl1 = ws;                            // NN*128
    float* xr1 = ws + (size_t)NN * 128;         // NN*128; h1 aliases (per-row RAW only)
    float* h1  = xr1;
    float* xl2 = ws + (size_t)NN * 256;         // NN*32
    float* xr2 = xl2 + (size_t)NN * 32;         // NN*32; h2 aliases
    float* h2  = xr2;
    float* pool = xr2 + (size_t)NN * 32;        // NG*32
    float* cnt  = pool + (size_t)NG * 32;       // NG
    int* ib       = (int*)(cnt + NG);
    int* deg      = ib;                         // NN (reused as cursor)
    int* rowstart = ib + NN;                    // NN+1
    int* bsum     = ib + 2 * NN + 1;            // 512
    int* csr_src  = ib + 2 * NN + 1 + 512;      // ET

    // ---- CSR build ----
    hipMemsetAsync(deg, 0, NN * sizeof(int), stream);
    hipMemsetAsync(pool, 0, (size_t)(NG * 33) * sizeof(float), stream);
    hist_kernel<<<(ET + 255) / 256, 256, 0, stream>>>(edst, deg);
    scan1_kernel<<<NB1, 256, 0, stream>>>(deg, rowstart, bsum);
    scan2_kernel<<<1, 512, 0, stream>>>(bsum);
    scan3_kernel<<<NB1, 256, 0, stream>>>(rowstart, bsum);
    hipMemsetAsync(deg, 0, NN * sizeof(int), stream);   // -> cursor
    scatter_kernel<<<(ET + 255) / 256, 256, 0, stream>>>(esrc, edst, rowstart, deg, csr_src);

    // ---- layer 1 ----
    transform_kernel<64, 128, 1, 64><<<(NN + 63) / 64, 256, 0, stream>>>(
        x, Wl1, bl1, Wr1, br1, xl1, xr1, NN);
    gat1_kernel<<<(NN + 3) / 4, 256, 0, stream>>>(
        rowstart, csr_src, xl1, xr1, att1, bias1, h1);

    // ---- layer 2 ----
    transform_kernel<128, 32, 4, 64><<<(NN + 63) / 64, 256, 0, stream>>>(
        h1, Wl2, bl2, Wr2, br2, xl2, xr2, NN);
    gat2_kernel<<<(NN + 7) / 8, 256, 0, stream>>>(
        rowstart, csr_src, xl2, xr2, att2, h2);

    // ---- pool + head ----
    pool_kernel<<<(NN + 255) / 256, 256, 0, stream>>>(h2, bias2, batch, pool, cnt);
    head_kernel<<<NG, 64, 0, stream>>>(pool, cnt, Wh1, bh1, Wh2, bh2, (float*)d_out);
}

// Round 4
// 501.241 us; speedup vs baseline: 3.1405x; 3.1405x over previous
//
#include <hip/hip_runtime.h>
#include <math.h>

#define NN 100000
#define NE 800000
#define ET (NN + NE)   /* 900000 edges incl self-loops */
#define GIN 64
#define CH 32
#define NH 4
#define NG 256
#define SLOPE 0.2f
#define NB1 ((NN + 255) / 256)   /* 391 scan blocks */

// ---- node transform: XL = X@Wl+bl, XR = X@Wr+br ----
// W columns in registers (split across TPC lanes), X tile staged in LDS.
// threads = 2*M*TPC = 256. Each thread: col = t/TPC, k-slice = t%TPC.
// __launch_bounds__(256,2): VGPR cap 256 so wreg[KR] stays in registers
// (default heuristic capped at 64 -> wreg spilled to scratch -> 2.7 GB fetch, R2).
template<int K, int M, int TPC, int NPB>
__global__ __launch_bounds__(256, 2)
void transform_kernel(const float* __restrict__ X,
                      const float* __restrict__ Wl, const float* __restrict__ bl,
                      const float* __restrict__ Wr, const float* __restrict__ br,
                      float* __restrict__ XL, float* __restrict__ XR, int n)
{
    constexpr int KR = K / TPC;            // W regs per thread
    __shared__ float sX[NPB * K];
    const int t   = threadIdx.x;
    const int col = t / TPC;               // 0..2M-1
    const int ks  = t % TPC;
    const int k0  = ks * KR;
    const int cw  = (col < M) ? col : col - M;
    const float* W = (col < M) ? Wl : Wr;
    float wreg[KR];
    #pragma unroll
    for (int k = 0; k < KR; ++k) wreg[k] = W[(size_t)(k0 + k) * M + cw];
    const float bias = (ks == 0) ? ((col < M) ? bl[cw] : br[cw]) : 0.f;
    float* const outp = (col < M) ? XL : XR;

    const int base   = blockIdx.x * NPB;
    const int nvalid = (n - base < NPB) ? (n - base) : NPB;

    // stage X tile (coalesced float4)
    constexpr int QTOT = NPB * K / 4;
    for (int q = t; q < QTOT; q += 256) {
        const int node = q / (K / 4);
        const int qq   = q % (K / 4);
        float4 v = (node < nvalid)
                       ? *(const float4*)(X + (size_t)(base + node) * K + qq * 4)
                       : make_float4(0.f, 0.f, 0.f, 0.f);
        *(float4*)(sX + node * K + qq * 4) = v;
    }
    __syncthreads();

    for (int nn0 = 0; nn0 < nvalid; nn0 += 2) {
        float acc0 = bias, acc1 = bias;
        const float* x0 = sX + nn0 * K + k0;
        const float* x1 = sX + (nn0 + 1) * K + k0;   // safe: NPB even, zero-filled
        const bool has1 = (nn0 + 1 < nvalid);
        #pragma unroll
        for (int kq = 0; kq < KR / 4; ++kq) {
            const float4 a = *(const float4*)(x0 + kq * 4);
            acc0 = fmaf(a.x, wreg[kq * 4 + 0], acc0);
            acc0 = fmaf(a.y, wreg[kq * 4 + 1], acc0);
            acc0 = fmaf(a.z, wreg[kq * 4 + 2], acc0);
            acc0 = fmaf(a.w, wreg[kq * 4 + 3], acc0);
            const float4 b = *(const float4*)(x1 + kq * 4);
            acc1 = fmaf(b.x, wreg[kq * 4 + 0], acc1);
            acc1 = fmaf(b.y, wreg[kq * 4 + 1], acc1);
            acc1 = fmaf(b.z, wreg[kq * 4 + 2], acc1);
            acc1 = fmaf(b.w, wreg[kq * 4 + 3], acc1);
        }
        if (TPC > 1) {
            #pragma unroll
            for (int off = 1; off < TPC; off <<= 1) {
                acc0 += __shfl_xor(acc0, off);
                acc1 += __shfl_xor(acc1, off);
            }
        }
        if (ks == 0) {
            outp[(size_t)(base + nn0) * M + cw] = acc0;
            if (has1) outp[(size_t)(base + nn0 + 1) * M + cw] = acc1;
        }
    }
}

// ---- CSR build: histogram of dst ----
__global__ void hist_kernel(const int* __restrict__ edst, int* __restrict__ deg)
{
    int e = blockIdx.x * 256 + threadIdx.x;
    if (e >= ET) return;
    int d = (e < NE) ? edst[e] : (e - NE);
    atomicAdd(deg + d, 1);
}

// ---- 3-kernel exclusive scan: rowstart[i] = sum(deg[0..i-1]) ----
__global__ void scan1_kernel(const int* __restrict__ deg, int* __restrict__ rowstart,
                             int* __restrict__ bsum)
{
    __shared__ int lds[256];
    int t = threadIdx.x, idx = blockIdx.x * 256 + t;
    int v = (idx < NN) ? deg[idx] : 0;
    lds[t] = v;
    __syncthreads();
    #pragma unroll
    for (int off = 1; off < 256; off <<= 1) {
        int add = (t >= off) ? lds[t - off] : 0;
        __syncthreads();
        lds[t] += add;
        __syncthreads();
    }
    if (idx < NN) rowstart[idx + 1] = lds[t];   // inclusive, block-local
    if (t == 255) bsum[blockIdx.x] = lds[255];
}

__global__ void scan2_kernel(int* __restrict__ bsum)   // exclusive scan of NB1 sums
{
    __shared__ int lds[512];
    int t = threadIdx.x;
    int v = (t < NB1) ? bsum[t] : 0;
    lds[t] = v;
    __syncthreads();
    #pragma unroll
    for (int off = 1; off < 512; off <<= 1) {
        int add = (t >= off) ? lds[t - off] : 0;
        __syncthreads();
        lds[t] += add;
        __syncthreads();
    }
    if (t < NB1) bsum[t] = lds[t] - v;
}

__global__ void scan3_kernel(int* __restrict__ rowstart, const int* __restrict__ bsum)
{
    int idx = blockIdx.x * 256 + threadIdx.x;
    if (idx == 0) rowstart[0] = 0;
    if (idx < NN) rowstart[idx + 1] += bsum[blockIdx.x];
}

// ---- CSR scatter: fill src ids per dst row ----
__global__ void scatter_kernel(const int* __restrict__ esrc, const int* __restrict__ edst,
                               const int* __restrict__ rowstart,
                               int* __restrict__ cursor, int* __restrict__ csr_src)
{
    int e = blockIdx.x * 256 + threadIdx.x;
    if (e >= ET) return;
    int s, d;
    if (e < NE) { s = esrc[e]; d = edst[e]; } else { s = e - NE; d = s; }
    int pos = rowstart[d] + atomicAdd(cursor + d, 1);
    csr_src[pos] = s;
}

// ---- layer 1 fused GATv2 (H=4, C=32): one wave per dst node, online softmax ----
__global__ void gat1_kernel(const int* __restrict__ rowstart, const int* __restrict__ csr_src,
                            const float* __restrict__ XL, const float* __restrict__ XR,
                            const float* __restrict__ att, const float* __restrict__ bias,
                            float* __restrict__ H1)
{
    int node = blockIdx.x * 4 + (threadIdx.x >> 6);
    if (node >= NN) return;
    const int lane = threadIdx.x & 63;
    const int c0 = lane * 2;
    const float2 xr = *(const float2*)(XR + (size_t)node * 128 + c0);
    const float2 at = *(const float2*)(att + c0);
    const int beg = rowstart[node], end = rowstart[node + 1];
    float m = -INFINITY, ssum = 0.f, acc0 = 0.f, acc1 = 0.f;
    for (int i = beg; i < end; ++i) {
        const int s = csr_src[i];
        const float2 xl = *(const float2*)(XL + (size_t)s * 128 + c0);
        float v0 = xl.x + xr.x; v0 = v0 > 0.f ? v0 : SLOPE * v0;
        float v1 = xl.y + xr.y; v1 = v1 > 0.f ? v1 : SLOPE * v1;
        float p = fmaf(v0, at.x, v1 * at.y);
        p += __shfl_xor(p, 1);
        p += __shfl_xor(p, 2);
        p += __shfl_xor(p, 4);
        p += __shfl_xor(p, 8);       // p = alpha for head (lane>>4)
        float ea;
        if (p > m) {
            float sc = expf(m - p);  // exp(-inf)=0 on first edge
            ssum *= sc; acc0 *= sc; acc1 *= sc;
            m = p; ea = 1.f;
        } else {
            ea = expf(p - m);
        }
        ssum += ea;
        acc0 = fmaf(ea, xl.x, acc0);
        acc1 = fmaf(ea, xl.y, acc1);
    }
    const float inv = 1.f / (ssum + 1e-16f);
    float o0 = acc0 * inv + bias[c0];
    float o1 = acc1 * inv + bias[c0 + 1];
    o0 = o0 > 0.f ? o0 : expm1f(o0);
    o1 = o1 > 0.f ? o1 : expm1f(o1);
    *(float2*)(H1 + (size_t)node * 128 + c0) = make_float2(o0, o1);
}

// ---- layer 2 fused GATv2 (H=1, C=32): one half-wave per dst node ----
__global__ void gat2_kernel(const int* __restrict__ rowstart, const int* __restrict__ csr_src,
                            const float* __restrict__ XL, const float* __restrict__ XR,
                            const float* __restrict__ att,
                            float* __restrict__ H2)
{
    int node = blockIdx.x * 8 + (threadIdx.x >> 5);
    if (node >= NN) return;
    const int c = threadIdx.x & 31;
    const float xr = XR[(size_t)node * 32 + c];
    const float at = att[c];
    const int beg = rowstart[node], end = rowstart[node + 1];
    float m = -INFINITY, ssum = 0.f, acc = 0.f;
    for (int i = beg; i < end; ++i) {
        const int s = csr_src[i];
        const float xl = XL[(size_t)s * 32 + c];
        float v = xl + xr; v = v > 0.f ? v : SLOPE * v;
        float p = v * at;
        p += __shfl_xor(p, 1);
        p += __shfl_xor(p, 2);
        p += __shfl_xor(p, 4);
        p += __shfl_xor(p, 8);
        p += __shfl_xor(p, 16);
        float ea;
        if (p > m) {
            float sc = expf(m - p);
            ssum *= sc; acc *= sc;
            m = p; ea = 1.f;
        } else {
            ea = expf(p - m);
        }
        ssum += ea;
        acc = fmaf(ea, xl, acc);
    }
    H2[(size_t)node * 32 + c] = acc / (ssum + 1e-16f);
}

// ---- mean-pool (batch sorted: run-length accumulate, then atomic flush) ----
__global__ void pool_kernel(const float* __restrict__ h2, const float* __restrict__ bias2,
                            const int* __restrict__ batch,
                            float* __restrict__ pool, float* __restrict__ cnt)
{
    const int c    = threadIdx.x & 31;
    const int slot = threadIdx.x >> 5;     // 0..7
    const int base = blockIdx.x * 256;
    const float b = bias2[c];
    float acc = 0.f, cacc = 0.f;
    int curg = -1;
    for (int i = slot; i < 256; i += 8) {
        int node = base + i;
        if (node >= NN) break;
        int g = batch[node];
        if (g != curg) {
            if (curg >= 0) {
                atomicAdd(pool + (size_t)curg * 32 + c, acc);
                if (c == 0) atomicAdd(cnt + curg, cacc);
            }
            acc = 0.f; cacc = 0.f; curg = g;
        }
        acc += h2[(size_t)node * 32 + c] + b;
        cacc += 1.f;
    }
    if (curg >= 0) {
        atomicAdd(pool + (size_t)curg * 32 + c, acc);
        if (c == 0) atomicAdd(cnt + curg, cacc);
    }
}

// ---- per-graph head MLP: out = relu(pooled@Wh1+bh1)@Wh2 + bh2 ----
__global__ void head_kernel(const float* __restrict__ pool, const float* __restrict__ cnt,
                            const float* __restrict__ Wh1, const float* __restrict__ bh1,
                            const float* __restrict__ Wh2, const float* __restrict__ bh2,
                            float* __restrict__ out)
{
    int g = blockIdx.x;
    int c = threadIdx.x;      // 0..63
    float partial = 0.f;
    if (c < 32) {
        float invc = 1.f / fmaxf(cnt[g], 1.f);
        float acc = bh1[c];
        #pragma unroll
        for (int k = 0; k < 32; ++k)
            acc = fmaf(pool[g * 32 + k] * invc, Wh1[k * 32 + c], acc);
        float z = fmaxf(acc, 0.f);
        partial = z * Wh2[c];
    }
    #pragma unroll
    for (int off = 32; off >= 1; off >>= 1)
        partial += __shfl_down(partial, off);
    if (c == 0) out[g] = partial + bh2[0];
}

extern "C" void kernel_launch(void* const* d_in, const int* in_sizes, int n_in,
                              void* d_out, int out_size, void* d_ws, size_t ws_size,
                              hipStream_t stream)
{
    const float* x     = (const float*)d_in[0];
    const int*   ei    = (const int*)d_in[1];
    const int*   batch = (const int*)d_in[2];
    const float* Wl1   = (const float*)d_in[3];
    const float* bl1   = (const float*)d_in[4];
    const float* Wr1   = (const float*)d_in[5];
    const float* br1   = (const float*)d_in[6];
    const float* att1  = (const float*)d_in[7];
    const float* bias1 = (const float*)d_in[8];
    const float* Wl2   = (const float*)d_in[9];
    const float* bl2   = (const float*)d_in[10];
    const float* Wr2   = (const float*)d_in[11];
    const float* br2   = (const float*)d_in[12];
    const float* att2  = (const float*)d_in[13];
    const float* bias2 = (const float*)d_in[14];
    const float* Wh1   = (const float*)d_in[15];
    const float* bh1   = (const float*)d_in[16];
    const float* Wh2   = (const float*)d_in[17];
    const float* bh2   = (const float*)d_in[18];
    const int* esrc = ei;
    const int* edst = ei + NE;

    // ---- workspace layout ----
    float* ws  = (float*)d_ws;
    float* xl1 = ws;                            // NN*128
    float* xr1 = ws + (size_t)NN * 128;         // NN*128; h1 aliases (per-row RAW only)
    float* h1  = xr1;
    float* xl2 = ws + (size_t)NN * 256;         // NN*32
    float* xr2 = xl2 + (size_t)NN * 32;         // NN*32; h2 aliases
    float* h2  = xr2;
    float* pool = xr2 + (size_t)NN * 32;        // NG*32
    float* cnt  = pool + (size_t)NG * 32;       // NG
    int* ib       = (int*)(cnt + NG);
    int* deg      = ib;                         // NN (reused as cursor)
    int* rowstart = ib + NN;                    // NN+1
    int* bsum     = ib + 2 * NN + 1;            // 512
    int* csr_src  = ib + 2 * NN + 1 + 512;      // ET

    // ---- CSR build ----
    hipMemsetAsync(deg, 0, NN * sizeof(int), stream);
    hipMemsetAsync(pool, 0, (size_t)(NG * 33) * sizeof(float), stream);
    hist_kernel<<<(ET + 255) / 256, 256, 0, stream>>>(edst, deg);
    scan1_kernel<<<NB1, 256, 0, stream>>>(deg, rowstart, bsum);
    scan2_kernel<<<1, 512, 0, stream>>>(bsum);
    scan3_kernel<<<NB1, 256, 0, stream>>>(rowstart, bsum);
    hipMemsetAsync(deg, 0, NN * sizeof(int), stream);   // -> cursor
    scatter_kernel<<<(ET + 255) / 256, 256, 0, stream>>>(esrc, edst, rowstart, deg, csr_src);

    // ---- layer 1 ----
    transform_kernel<64, 128, 1, 64><<<(NN + 63) / 64, 256, 0, stream>>>(
        x, Wl1, bl1, Wr1, br1, xl1, xr1, NN);
    gat1_kernel<<<(NN + 3) / 4, 256, 0, stream>>>(
        rowstart, csr_src, xl1, xr1, att1, bias1, h1);

    // ---- layer 2 ----
    transform_kernel<128, 32, 4, 64><<<(NN + 63) / 64, 256, 0, stream>>>(
        h1, Wl2, bl2, Wr2, br2, xl2, xr2, NN);
    gat2_kernel<<<(NN + 7) / 8, 256, 0, stream>>>(
        rowstart, csr_src, xl2, xr2, att2, h2);

    // ---- pool + head ----
    pool_kernel<<<(NN + 255) / 256, 256, 0, stream>>>(h2, bias2, batch, pool, cnt);
    head_kernel<<<NG, 64, 0, stream>>>(pool, cnt, Wh1, bh1, Wh2, bh2, (float*)d_out);
}

// Round 7
// 380.927 us; speedup vs baseline: 4.1325x; 1.3158x over previous
//
#include <hip/hip_runtime.h>
#include <hip/hip_fp16.h>
#include <math.h>

#define NN 100000
#define NE 800000
#define ET (NN + NE)   /* 900000 edges incl self-loops */
#define GIN 64
#define CH 32
#define NH 4
#define NG 256
#define SLOPE 0.2f
#define LOG2E 1.44269504088896340736f
#define NB1 ((NN + 255) / 256)   /* 391 scan blocks */

// ---- node transform: XLh = fp16(X@Wl+bl), XR = f32(X@Wr+br) ----
// W columns in registers, X tile staged in LDS. XL stored fp16: halves the
// random-gather bytes in the GAT kernels (attention math stays f32).
template<int K, int M, int TPC, int NPB>
__global__ __launch_bounds__(256, 2)
void transform_kernel(const float* __restrict__ X,
                      const float* __restrict__ Wl, const float* __restrict__ bl,
                      const float* __restrict__ Wr, const float* __restrict__ br,
                      __half* __restrict__ XLh, float* __restrict__ XR, int n)
{
    constexpr int KR = K / TPC;            // W regs per thread
    __shared__ float sX[NPB * K];
    const int t   = threadIdx.x;
    const int col = t / TPC;               // 0..2M-1
    const int ks  = t % TPC;
    const int k0  = ks * KR;
    const int cw  = (col < M) ? col : col - M;
    const float* W = (col < M) ? Wl : Wr;
    float wreg[KR];
    #pragma unroll
    for (int k = 0; k < KR; ++k) wreg[k] = W[(size_t)(k0 + k) * M + cw];
    const float bias = (ks == 0) ? ((col < M) ? bl[cw] : br[cw]) : 0.f;

    const int base   = blockIdx.x * NPB;
    const int nvalid = (n - base < NPB) ? (n - base) : NPB;

    // stage X tile (coalesced float4)
    constexpr int QTOT = NPB * K / 4;
    for (int q = t; q < QTOT; q += 256) {
        const int node = q / (K / 4);
        const int qq   = q % (K / 4);
        float4 v = (node < nvalid)
                       ? *(const float4*)(X + (size_t)(base + node) * K + qq * 4)
                       : make_float4(0.f, 0.f, 0.f, 0.f);
        *(float4*)(sX + node * K + qq * 4) = v;
    }
    __syncthreads();

    for (int nn0 = 0; nn0 < nvalid; nn0 += 2) {
        float acc0 = bias, acc1 = bias;
        const float* x0 = sX + nn0 * K + k0;
        const float* x1 = sX + (nn0 + 1) * K + k0;   // safe: NPB even, zero-filled
        const bool has1 = (nn0 + 1 < nvalid);
        #pragma unroll
        for (int kq = 0; kq < KR / 4; ++kq) {
            const float4 a = *(const float4*)(x0 + kq * 4);
            acc0 = fmaf(a.x, wreg[kq * 4 + 0], acc0);
            acc0 = fmaf(a.y, wreg[kq * 4 + 1], acc0);
            acc0 = fmaf(a.z, wreg[kq * 4 + 2], acc0);
            acc0 = fmaf(a.w, wreg[kq * 4 + 3], acc0);
            const float4 b = *(const float4*)(x1 + kq * 4);
            acc1 = fmaf(b.x, wreg[kq * 4 + 0], acc1);
            acc1 = fmaf(b.y, wreg[kq * 4 + 1], acc1);
            acc1 = fmaf(b.z, wreg[kq * 4 + 2], acc1);
            acc1 = fmaf(b.w, wreg[kq * 4 + 3], acc1);
        }
        if (TPC > 1) {
            #pragma unroll
            for (int off = 1; off < TPC; off <<= 1) {
                acc0 += __shfl_xor(acc0, off);
                acc1 += __shfl_xor(acc1, off);
            }
        }
        if (ks == 0) {
            if (col < M) {
                XLh[(size_t)(base + nn0) * M + cw] = __float2half(acc0);
                if (has1) XLh[(size_t)(base + nn0 + 1) * M + cw] = __float2half(acc1);
            } else {
                XR[(size_t)(base + nn0) * M + cw] = acc0;
                if (has1) XR[(size_t)(base + nn0 + 1) * M + cw] = acc1;
            }
        }
    }
}

// ---- CSR build: histogram of dst ----
__global__ void hist_kernel(const int* __restrict__ edst, int* __restrict__ deg)
{
    int e = blockIdx.x * 256 + threadIdx.x;
    if (e >= ET) return;
    int d = (e < NE) ? edst[e] : (e - NE);
    atomicAdd(deg + d, 1);
}

// ---- 3-kernel exclusive scan ----
__global__ void scan1_kernel(const int* __restrict__ deg, int* __restrict__ rowstart,
                             int* __restrict__ bsum)
{
    __shared__ int lds[256];
    int t = threadIdx.x, idx = blockIdx.x * 256 + t;
    int v = (idx < NN) ? deg[idx] : 0;
    lds[t] = v;
    __syncthreads();
    #pragma unroll
    for (int off = 1; off < 256; off <<= 1) {
        int add = (t >= off) ? lds[t - off] : 0;
        __syncthreads();
        lds[t] += add;
        __syncthreads();
    }
    if (idx < NN) rowstart[idx + 1] = lds[t];
    if (t == 255) bsum[blockIdx.x] = lds[255];
}

__global__ void scan2_kernel(int* __restrict__ bsum)
{
    __shared__ int lds[512];
    int t = threadIdx.x;
    int v = (t < NB1) ? bsum[t] : 0;
    lds[t] = v;
    __syncthreads();
    #pragma unroll
    for (int off = 1; off < 512; off <<= 1) {
        int add = (t >= off) ? lds[t - off] : 0;
        __syncthreads();
        lds[t] += add;
        __syncthreads();
    }
    if (t < NB1) bsum[t] = lds[t] - v;
}

__global__ void scan3_kernel(int* __restrict__ rowstart, const int* __restrict__ bsum)
{
    int idx = blockIdx.x * 256 + threadIdx.x;
    if (idx == 0) rowstart[0] = 0;
    if (idx < NN) rowstart[idx + 1] += bsum[blockIdx.x];
}

// ---- CSR scatter ----
__global__ void scatter_kernel(const int* __restrict__ esrc, const int* __restrict__ edst,
                               const int* __restrict__ rowstart,
                               int* __restrict__ cursor, int* __restrict__ csr_src)
{
    int e = blockIdx.x * 256 + threadIdx.x;
    if (e >= ET) return;
    int s, d;
    if (e < NE) { s = esrc[e]; d = edst[e]; } else { s = e - NE; d = s; }
    int pos = rowstart[d] + atomicAdd(cursor + d, 1);
    csr_src[pos] = s;
}

// ---- layer 1 fused GATv2 (H=4, C=32): one wave per node; edge-pair unrolled,
// branchless base-2 online softmax; fp16 gathers ----
__global__ void gat1_kernel(const int* __restrict__ rowstart, const int* __restrict__ csr_src,
                            const __half* __restrict__ XLh, const float* __restrict__ XR,
                            const float* __restrict__ att, const float* __restrict__ bias,
                            float* __restrict__ H1)
{
    int node = blockIdx.x * 4 + (threadIdx.x >> 6);
    if (node >= NN) return;
    const int lane = threadIdx.x & 63;
    const int c0 = lane * 2;
    const float2 xr = *(const float2*)(XR + (size_t)node * 128 + c0);
    float2 at = *(const float2*)(att + c0);
    at.x *= LOG2E; at.y *= LOG2E;            // base-2 softmax (exact rescale)
    const int beg = rowstart[node], end = rowstart[node + 1];
    float m = -INFINITY, ssum = 0.f, acc0 = 0.f, acc1 = 0.f;
    int i = beg;
    for (; i + 2 <= end; i += 2) {
        const int s0 = csr_src[i];
        const int s1 = csr_src[i + 1];
        const float2 x0 = __half22float2(*(const __half2*)(XLh + (size_t)s0 * 128 + c0));
        const float2 x1 = __half22float2(*(const __half2*)(XLh + (size_t)s1 * 128 + c0));
        float a0 = x0.x + xr.x; a0 = a0 > 0.f ? a0 : SLOPE * a0;
        float b0 = x0.y + xr.y; b0 = b0 > 0.f ? b0 : SLOPE * b0;
        float a1 = x1.x + xr.x; a1 = a1 > 0.f ? a1 : SLOPE * a1;
        float b1 = x1.y + xr.y; b1 = b1 > 0.f ? b1 : SLOPE * b1;
        float p0 = fmaf(a0, at.x, b0 * at.y);
        float p1 = fmaf(a1, at.x, b1 * at.y);
        p0 += __shfl_xor(p0, 1);  p1 += __shfl_xor(p1, 1);
        p0 += __shfl_xor(p0, 2);  p1 += __shfl_xor(p1, 2);
        p0 += __shfl_xor(p0, 4);  p1 += __shfl_xor(p1, 4);
        p0 += __shfl_xor(p0, 8);  p1 += __shfl_xor(p1, 8);   // per-head logit (log2 units)
        const float mn = fmaxf(m, fmaxf(p0, p1));
        const float sc = exp2f(m - mn);       // exp2(-inf)=0 on first pair
        const float e0 = exp2f(p0 - mn);
        const float e1 = exp2f(p1 - mn);
        ssum = fmaf(ssum, sc, e0 + e1);
        acc0 = fmaf(acc0, sc, fmaf(e0, x0.x, e1 * x1.x));
        acc1 = fmaf(acc1, sc, fmaf(e0, x0.y, e1 * x1.y));
        m = mn;
    }
    if (i < end) {
        const int s0 = csr_src[i];
        const float2 x0 = __half22float2(*(const __half2*)(XLh + (size_t)s0 * 128 + c0));
        float a0 = x0.x + xr.x; a0 = a0 > 0.f ? a0 : SLOPE * a0;
        float b0 = x0.y + xr.y; b0 = b0 > 0.f ? b0 : SLOPE * b0;
        float p0 = fmaf(a0, at.x, b0 * at.y);
        p0 += __shfl_xor(p0, 1);
        p0 += __shfl_xor(p0, 2);
        p0 += __shfl_xor(p0, 4);
        p0 += __shfl_xor(p0, 8);
        const float mn = fmaxf(m, p0);
        const float sc = exp2f(m - mn);
        const float e0 = exp2f(p0 - mn);
        ssum = fmaf(ssum, sc, e0);
        acc0 = fmaf(acc0, sc, e0 * x0.x);
        acc1 = fmaf(acc1, sc, e0 * x0.y);
    }
    const float inv = 1.f / (ssum + 1e-16f);
    float o0 = acc0 * inv + bias[c0];
    float o1 = acc1 * inv + bias[c0 + 1];
    o0 = o0 > 0.f ? o0 : expm1f(o0);
    o1 = o1 > 0.f ? o1 : expm1f(o1);
    *(float2*)(H1 + (size_t)node * 128 + c0) = make_float2(o0, o1);
}

// ---- layer 2 fused GATv2 (H=1, C=32): half-wave per node; same structure ----
__global__ void gat2_kernel(const int* __restrict__ rowstart, const int* __restrict__ csr_src,
                            const __half* __restrict__ XLh, const float* __restrict__ XR,
                            const float* __restrict__ att,
                            float* __restrict__ H2)
{
    int node = blockIdx.x * 8 + (threadIdx.x >> 5);
    if (node >= NN) return;
    const int c = threadIdx.x & 31;
    const float xr = XR[(size_t)node * 32 + c];
    const float at = att[c] * LOG2E;
    const int beg = rowstart[node], end = rowstart[node + 1];
    float m = -INFINITY, ssum = 0.f, acc = 0.f;
    int i = beg;
    for (; i + 2 <= end; i += 2) {
        const int s0 = csr_src[i];
        const int s1 = csr_src[i + 1];
        const float x0 = __half2float(XLh[(size_t)s0 * 32 + c]);
        const float x1 = __half2float(XLh[(size_t)s1 * 32 + c]);
        float v0 = x0 + xr; v0 = v0 > 0.f ? v0 : SLOPE * v0;
        float v1 = x1 + xr; v1 = v1 > 0.f ? v1 : SLOPE * v1;
        float p0 = v0 * at;
        float p1 = v1 * at;
        p0 += __shfl_xor(p0, 1);   p1 += __shfl_xor(p1, 1);
        p0 += __shfl_xor(p0, 2);   p1 += __shfl_xor(p1, 2);
        p0 += __shfl_xor(p0, 4);   p1 += __shfl_xor(p1, 4);
        p0 += __shfl_xor(p0, 8);   p1 += __shfl_xor(p1, 8);
        p0 += __shfl_xor(p0, 16);  p1 += __shfl_xor(p1, 16);
        const float mn = fmaxf(m, fmaxf(p0, p1));
        const float sc = exp2f(m - mn);
        const float e0 = exp2f(p0 - mn);
        const float e1 = exp2f(p1 - mn);
        ssum = fmaf(ssum, sc, e0 + e1);
        acc  = fmaf(acc,  sc, fmaf(e0, x0, e1 * x1));
        m = mn;
    }
    if (i < end) {
        const int s0 = csr_src[i];
        const float x0 = __half2float(XLh[(size_t)s0 * 32 + c]);
        float v0 = x0 + xr; v0 = v0 > 0.f ? v0 : SLOPE * v0;
        float p0 = v0 * at;
        p0 += __shfl_xor(p0, 1);
        p0 += __shfl_xor(p0, 2);
        p0 += __shfl_xor(p0, 4);
        p0 += __shfl_xor(p0, 8);
        p0 += __shfl_xor(p0, 16);
        const float mn = fmaxf(m, p0);
        const float sc = exp2f(m - mn);
        const float e0 = exp2f(p0 - mn);
        ssum = fmaf(ssum, sc, e0);
        acc  = fmaf(acc,  sc, e0 * x0);
    }
    H2[(size_t)node * 32 + c] = acc / (ssum + 1e-16f);
}

// ---- mean-pool (batch sorted: run-length accumulate, then atomic flush) ----
__global__ void pool_kernel(const float* __restrict__ h2, const float* __restrict__ bias2,
                            const int* __restrict__ batch,
                            float* __restrict__ pool, float* __restrict__ cnt)
{
    const int c    = threadIdx.x & 31;
    const int slot = threadIdx.x >> 5;     // 0..7
    const int base = blockIdx.x * 256;
    const float b = bias2[c];
    float acc = 0.f, cacc = 0.f;
    int curg = -1;
    for (int i = slot; i < 256; i += 8) {
        int node = base + i;
        if (node >= NN) break;
        int g = batch[node];
        if (g != curg) {
            if (curg >= 0) {
                atomicAdd(pool + (size_t)curg * 32 + c, acc);
                if (c == 0) atomicAdd(cnt + curg, cacc);
            }
            acc = 0.f; cacc = 0.f; curg = g;
        }
        acc += h2[(size_t)node * 32 + c] + b;
        cacc += 1.f;
    }
    if (curg >= 0) {
        atomicAdd(pool + (size_t)curg * 32 + c, acc);
        if (c == 0) atomicAdd(cnt + curg, cacc);
    }
}

// ---- per-graph head MLP ----
__global__ void head_kernel(const float* __restrict__ pool, const float* __restrict__ cnt,
                            const float* __restrict__ Wh1, const float* __restrict__ bh1,
                            const float* __restrict__ Wh2, const float* __restrict__ bh2,
                            float* __restrict__ out)
{
    int g = blockIdx.x;
    int c = threadIdx.x;      // 0..63
    float partial = 0.f;
    if (c < 32) {
        float invc = 1.f / fmaxf(cnt[g], 1.f);
        float acc = bh1[c];
        #pragma unroll
        for (int k = 0; k < 32; ++k)
            acc = fmaf(pool[g * 32 + k] * invc, Wh1[k * 32 + c], acc);
        float z = fmaxf(acc, 0.f);
        partial = z * Wh2[c];
    }
    #pragma unroll
    for (int off = 32; off >= 1; off >>= 1)
        partial += __shfl_down(partial, off);
    if (c == 0) out[g] = partial + bh2[0];
}

extern "C" void kernel_launch(void* const* d_in, const int* in_sizes, int n_in,
                              void* d_out, int out_size, void* d_ws, size_t ws_size,
                              hipStream_t stream)
{
    const float* x     = (const float*)d_in[0];
    const int*   ei    = (const int*)d_in[1];
    const int*   batch = (const int*)d_in[2];
    const float* Wl1   = (const float*)d_in[3];
    const float* bl1   = (const float*)d_in[4];
    const float* Wr1   = (const float*)d_in[5];
    const float* br1   = (const float*)d_in[6];
    const float* att1  = (const float*)d_in[7];
    const float* bias1 = (const float*)d_in[8];
    const float* Wl2   = (const float*)d_in[9];
    const float* bl2   = (const float*)d_in[10];
    const float* Wr2   = (const float*)d_in[11];
    const float* br2   = (const float*)d_in[12];
    const float* att2  = (const float*)d_in[13];
    const float* bias2 = (const float*)d_in[14];
    const float* Wh1   = (const float*)d_in[15];
    const float* bh1   = (const float*)d_in[16];
    const float* Wh2   = (const float*)d_in[17];
    const float* bh2   = (const float*)d_in[18];
    const int* esrc = ei;
    const int* edst = ei + NE;

    // ---- workspace layout (bytes) ----
    char* wsb = (char*)d_ws;
    __half* xl1h = (__half*)wsb;                               // NN*128*2 = 25.6 MB
    float*  xr1  = (float*)(wsb + (size_t)NN * 128 * 2);       // NN*128*4 = 51.2 MB
    float*  h1   = xr1;                                        // alias (per-row RAW in-wave)
    char* p2 = wsb + (size_t)NN * 128 * 2 + (size_t)NN * 128 * 4;
    __half* xl2h = (__half*)p2;                                // NN*32*2 = 6.4 MB
    float*  xr2  = (float*)(p2 + (size_t)NN * 32 * 2);         // NN*32*4 = 12.8 MB
    float*  h2   = xr2;                                        // alias
    float*  pool = (float*)(p2 + (size_t)NN * 32 * 2 + (size_t)NN * 32 * 4);
    float*  cnt  = pool + (size_t)NG * 32;                     // NG
    int* ib       = (int*)(cnt + NG);
    int* deg      = ib;                                        // NN (reused as cursor)
    int* rowstart = ib + NN;                                   // NN+1
    int* bsum     = ib + 2 * NN + 1;                           // 512
    int* csr_src  = ib + 2 * NN + 1 + 512;                     // ET

    // ---- CSR build ----
    hipMemsetAsync(deg, 0, NN * sizeof(int), stream);
    hipMemsetAsync(pool, 0, (size_t)(NG * 33) * sizeof(float), stream);
    hist_kernel<<<(ET + 255) / 256, 256, 0, stream>>>(edst, deg);
    scan1_kernel<<<NB1, 256, 0, stream>>>(deg, rowstart, bsum);
    scan2_kernel<<<1, 512, 0, stream>>>(bsum);
    scan3_kernel<<<NB1, 256, 0, stream>>>(rowstart, bsum);
    hipMemsetAsync(deg, 0, NN * sizeof(int), stream);   // -> cursor
    scatter_kernel<<<(ET + 255) / 256, 256, 0, stream>>>(esrc, edst, rowstart, deg, csr_src);

    // ---- layer 1 ----
    transform_kernel<64, 128, 1, 64><<<(NN + 63) / 64, 256, 0, stream>>>(
        x, Wl1, bl1, Wr1, br1, xl1h, xr1, NN);
    gat1_kernel<<<(NN + 3) / 4, 256, 0, stream>>>(
        rowstart, csr_src, xl1h, xr1, att1, bias1, h1);

    // ---- layer 2 ----
    transform_kernel<128, 32, 4, 64><<<(NN + 63) / 64, 256, 0, stream>>>(
        h1, Wl2, bl2, Wr2, br2, xl2h, xr2, NN);
    gat2_kernel<<<(NN + 7) / 8, 256, 0, stream>>>(
        rowstart, csr_src, xl2h, xr2, att2, h2);

    // ---- pool + head ----
    pool_kernel<<<(NN + 255) / 256, 256, 0, stream>>>(h2, bias2, batch, pool, cnt);
    head_kernel<<<NG, 64, 0, stream>>>(pool, cnt, Wh1, bh1, Wh2, bh2, (float*)d_out);
}